// Round 2
// baseline (9.750 us; speedup 1.0000x reference)
//
#include <hip/hip_runtime.h>

// QuantumLayer: 4-qubit RX(x)/RY(w) + CNOT chain + <Z_i> readout.
// Analytic identity: out[b][i] = prod_{j<=i} cos(x[b][j]) * cos(w[j]).
// Derivation: pre-CNOT state is a product state with per-qubit
// <Z_j> = cos(x_j)cos(w_j); Heisenberg conjugation of Z_i through the
// CNOT(0,1),CNOT(1,2),CNOT(2,3) chain yields Z_0...Z_i, whose product-state
// expectation factorizes.
//
// R2: native v_cos_f32 (input in revolutions; x*(1/2pi) is well inside the
// HW-valid range for N(0,1) inputs; abs err ~1e-6 vs 2e-2 threshold) +
// 2 float4 elements per thread with both loads issued up front (2x MLP,
// half the waves). This attacks the latency tail, not BW (8.4 MB total).

#define INV_2PI 0.15915494309189535f

__global__ void __launch_bounds__(256)
QuantumLayer_56607668961323_kernel(const float4* __restrict__ x,
                                   const float* __restrict__ w,
                                   float4* __restrict__ out,
                                   int n) {
    int i = (blockIdx.x * blockDim.x + threadIdx.x) * 2;

    // wave-uniform weight prefix products (4 cheap native cos, uniform)
    float cw0 = __builtin_amdgcn_cosf(w[0] * INV_2PI);
    float cw1 = cw0 * __builtin_amdgcn_cosf(w[1] * INV_2PI);
    float cw2 = cw1 * __builtin_amdgcn_cosf(w[2] * INV_2PI);
    float cw3 = cw2 * __builtin_amdgcn_cosf(w[3] * INV_2PI);

    if (i + 1 < n) {
        // both loads in flight before first use
        float4 a = x[i];
        float4 b = x[i + 1];

        float a0 = __builtin_amdgcn_cosf(a.x * INV_2PI);
        float a1 = a0 * __builtin_amdgcn_cosf(a.y * INV_2PI);
        float a2 = a1 * __builtin_amdgcn_cosf(a.z * INV_2PI);
        float a3 = a2 * __builtin_amdgcn_cosf(a.w * INV_2PI);
        out[i] = make_float4(a0 * cw0, a1 * cw1, a2 * cw2, a3 * cw3);

        float b0 = __builtin_amdgcn_cosf(b.x * INV_2PI);
        float b1 = b0 * __builtin_amdgcn_cosf(b.y * INV_2PI);
        float b2 = b1 * __builtin_amdgcn_cosf(b.z * INV_2PI);
        float b3 = b2 * __builtin_amdgcn_cosf(b.w * INV_2PI);
        out[i + 1] = make_float4(b0 * cw0, b1 * cw1, b2 * cw2, b3 * cw3);
    } else if (i < n) {
        float4 a = x[i];
        float a0 = __builtin_amdgcn_cosf(a.x * INV_2PI);
        float a1 = a0 * __builtin_amdgcn_cosf(a.y * INV_2PI);
        float a2 = a1 * __builtin_amdgcn_cosf(a.z * INV_2PI);
        float a3 = a2 * __builtin_amdgcn_cosf(a.w * INV_2PI);
        out[i] = make_float4(a0 * cw0, a1 * cw1, a2 * cw2, a3 * cw3);
    }
}

extern "C" void kernel_launch(void* const* d_in, const int* in_sizes, int n_in,
                              void* d_out, int out_size, void* d_ws, size_t ws_size,
                              hipStream_t stream) {
    const float4* x = (const float4*)d_in[0];   // (BATCH, 4) f32, read as float4
    const float*  w = (const float*)d_in[1];    // (4,) f32
    float4* out = (float4*)d_out;               // (BATCH, 4) f32, written as float4

    int n = in_sizes[0] / 4;                    // BATCH float4 elements
    int block = 256;
    int grid = (n + block * 2 - 1) / (block * 2);
    QuantumLayer_56607668961323_kernel<<<grid, block, 0, stream>>>(x, w, out, n);
}